// Round 9
// baseline (1176.906 us; speedup 1.0000x reference)
//
#include <hip/hip_runtime.h>
#include <hip/hip_bf16.h>

#define N_ROWS 100000
#define T_DIM  512
#define DIN    256
#define DH     256
#define KC     800
#define NSTEP  25      // KC / 32
#define NCHUNK 125     // 125 * 800 = 100000 exactly

typedef __attribute__((ext_vector_type(8))) short s16x8;
typedef __attribute__((ext_vector_type(4))) float f32x4;

// pack two f32 into bf16 pair (RTNE), low = lo, high = hi
static __device__ __forceinline__ unsigned bf16pair(float lo, float hi) {
  unsigned a = __builtin_bit_cast(unsigned, lo);
  unsigned b = __builtin_bit_cast(unsigned, hi);
  a = (a + 0x7fffu + ((a >> 16) & 1u)) >> 16;
  b = (b + 0x7fffu + ((b >> 16) & 1u)) & 0xffff0000u;
  return a | b;
}

// ---------------- Kernel 1: ve = H^T @ X as dense bf16 MFMA GEMM, split-K ----
__global__ __launch_bounds__(512, 2) void k_agg_mfma(
    const float* __restrict__ X, const float* __restrict__ Hm,
    float* __restrict__ ve, float* __restrict__ ve_part, int use_part)
{
  __shared__ unsigned smem[8192];   // A: [0,4096) u32, B: [4096,8192) ; 32 KB
  const int tid  = threadIdx.x;
  const int mt   = blockIdx.x & 1;
  const int kc   = blockIdx.x >> 1;
  const int m0   = mt * 256;
  const int k0   = kc * KC;
  const int lane = tid & 63;
  const int wv   = tid >> 6;        // 8 waves: 2 (wm) x 4 (wn)
  const int wm   = wv >> 2, wn = wv & 3;

  f32x4 acc[8][4] = {};

  const int kp0 = tid >> 6;
  const int kp1 = kp0 + 8;
  const int gg  = tid & 63;

  float4 ra0, ra1, ra2, ra3, rb0, rb1, rb2, rb3;

  auto load_tile = [&](int kt) {
    const size_t kb = (size_t)(k0 + kt * 32);
    const float* pa0 = &Hm[(kb + 2 * kp0) * T_DIM + m0 + gg * 4];
    ra0 = *(const float4*)pa0;
    ra1 = *(const float4*)(pa0 + T_DIM);
    const float* pa1 = &Hm[(kb + 2 * kp1) * T_DIM + m0 + gg * 4];
    ra2 = *(const float4*)pa1;
    ra3 = *(const float4*)(pa1 + T_DIM);
    const float* pb0 = &X[(kb + 2 * kp0) * DIN + gg * 4];
    rb0 = *(const float4*)pb0;
    rb1 = *(const float4*)(pb0 + DIN);
    const float* pb1 = &X[(kb + 2 * kp1) * DIN + gg * 4];
    rb2 = *(const float4*)pb1;
    rb3 = *(const float4*)(pb1 + DIN);
  };

  auto store_tile = [&]() {
#pragma unroll
    for (int d = 0; d < 4; ++d) {
      const int m  = gg * 4 + d;
      const int sw = d << 2;
      smem[m * 16 + (kp0 ^ sw)]        = bf16pair(((const float*)&ra0)[d], ((const float*)&ra1)[d]);
      smem[m * 16 + (kp1 ^ sw)]        = bf16pair(((const float*)&ra2)[d], ((const float*)&ra3)[d]);
      smem[4096 + m * 16 + (kp0 ^ sw)] = bf16pair(((const float*)&rb0)[d], ((const float*)&rb1)[d]);
      smem[4096 + m * 16 + (kp1 ^ sw)] = bf16pair(((const float*)&rb2)[d], ((const float*)&rb3)[d]);
    }
  };

  auto compute = [&]() {
    const uint4* sv = (const uint4*)smem;
    s16x8 af[8], bfr[4];
#pragma unroll
    for (int fm = 0; fm < 8; ++fm) {
      const int m = wm * 128 + fm * 16 + (lane & 15);
      af[fm] = __builtin_bit_cast(s16x8, sv[m * 4 + ((lane >> 4) ^ (m & 3))]);
    }
#pragma unroll
    for (int fn = 0; fn < 4; ++fn) {
      const int n = wn * 64 + fn * 16 + (lane & 15);
      bfr[fn] = __builtin_bit_cast(s16x8, sv[1024 + n * 4 + ((lane >> 4) ^ (n & 3))]);
    }
#pragma unroll
    for (int fm = 0; fm < 8; ++fm)
#pragma unroll
      for (int fn = 0; fn < 4; ++fn)
        acc[fm][fn] = __builtin_amdgcn_mfma_f32_16x16x32_bf16(af[fm], bfr[fn], acc[fm][fn], 0, 0, 0);
  };

  load_tile(0);
  store_tile();
  for (int kt = 0; kt < NSTEP; ++kt) {
    __syncthreads();
    if (kt + 1 < NSTEP) load_tile(kt + 1);
    compute();
    __syncthreads();
    if (kt + 1 < NSTEP) store_tile();
  }

  if (use_part) {
    float* dst = ve_part + (size_t)kc * (512 * 256);
#pragma unroll
    for (int fm = 0; fm < 8; ++fm) {
      const int r0 = m0 + wm * 128 + fm * 16 + (lane >> 4) * 4;
#pragma unroll
      for (int fn = 0; fn < 4; ++fn) {
        const int cc = wn * 64 + fn * 16 + (lane & 15);
#pragma unroll
        for (int q = 0; q < 4; ++q)
          dst[(size_t)(r0 + q) * 256 + cc] = acc[fm][fn][q];
      }
    }
  } else {
#pragma unroll
    for (int fm = 0; fm < 8; ++fm) {
      const int r0 = m0 + wm * 128 + fm * 16 + (lane >> 4) * 4;
#pragma unroll
      for (int fn = 0; fn < 4; ++fn) {
        const int cc = wn * 64 + fn * 16 + (lane & 15);
#pragma unroll
        for (int q = 0; q < 4; ++q)
          atomicAdd(&ve[(size_t)(r0 + q) * 256 + cc], acc[fm][fn][q]);
      }
    }
  }
}

// ---------------- Kernel 2: reduce split-K partials + gx = ve @ W_ih^T + b ----
__global__ __launch_bounds__(256) void k_gx(
    const float* __restrict__ vesrc, int npart,
    const float* __restrict__ Wih, const float* __restrict__ bih,
    float* __restrict__ gx)
{
  __shared__ float vl[DIN];
  const int t = blockIdx.x, j = threadIdx.x;
  float s = 0.f;
  for (int p = 0; p < npart; ++p) s += vesrc[(size_t)p * (512 * 256) + t * DIN + j];
  vl[j] = s;
  __syncthreads();
  float a0 = bih[j], a1 = bih[256 + j], a2 = bih[512 + j];
  const float* __restrict__ w0 = &Wih[(size_t)j * DIN];
  const float* __restrict__ w1 = &Wih[(size_t)(j + 256) * DIN];
  const float* __restrict__ w2 = &Wih[(size_t)(j + 512) * DIN];
#pragma unroll 4
  for (int k = 0; k < DIN; ++k) {
    const float v = vl[k];
    a0 = fmaf(w0[k], v, a0);
    a1 = fmaf(w1[k], v, a1);
    a2 = fmaf(w2[k], v, a2);
  }
  gx[t * 768 + j]       = a0;
  gx[t * 768 + 256 + j] = a1;
  gx[t * 768 + 512 + j] = a2;
}

// ---------------- Kernel 3: GRU scan via MFMA matvec + attention -------------
// 256 threads = 4 waves = 1 wave/SIMD. Wave w owns output dims [w*64,(w+1)*64)
// of ALL 3 gates = 192 rows of W_hh = 12 tiles x 8 k-blocks of A-fragments =
// 384 VGPRs + 48 acc + ~25 temps ~= 457 — within the measured no-spill range
// (<=450 ok, spills at 512; m08/m24). R2-R8 lesson: the RA always budgets for
// TWO concurrent workgroups (768thr->84, 512thr->128, 1024thr->64 regs), so a
// one-wg budget of 512 is only reachable by stating occupancy intent WITHOUT
// __launch_bounds__ (whose implied waves-per-eu metadata overrides the
// explicit attribute). NO __launch_bounds__ here — attributes only.
__global__ __attribute__((amdgpu_flat_work_group_size(256, 256),
                          amdgpu_waves_per_eu(1, 1)))
void k_gru_att(
    const float* __restrict__ Whh, const float* __restrict__ bhh,
    const float* __restrict__ gx, const float* __restrict__ watt,
    float* __restrict__ hs, float* __restrict__ out)
{
  __shared__ __hip_bfloat16 hb[DH];   // h_{t-1} as bf16 (512 B)
  __shared__ float ghs[768];          // gh + bias rows
  __shared__ float bsh[768];          // staged b_hh (acc init)
  __shared__ float sc[T_DIM];
  __shared__ float wa[DH];
  __shared__ float red[2];

  const int tid = threadIdx.x;
  const int w   = tid >> 6;   // wave 0..3
  const int l   = tid & 63;
  const int lr  = l & 15;     // row within 16-tile
  const int lg  = l >> 4;     // k-group / row-quad selector

  // tile (g,s) -> rows g*256 + w*64 + s*16  (g = gate, s = 16-row subtile)
  // Weight fragments: A[m=lr][k = kb*32 + lg*8 + 0..7] per lane. 384 VGPRs.
  s16x8 wf[12][8];
#pragma unroll
  for (int g = 0; g < 3; ++g) {
#pragma unroll
    for (int s = 0; s < 4; ++s) {
      const float* rp = &Whh[(size_t)(g * 256 + w * 64 + s * 16 + lr) * DH + lg * 8];
#pragma unroll
      for (int kb = 0; kb < 8; ++kb) {
        const float4 x0 = *(const float4*)(rp + kb * 32);
        const float4 x1 = *(const float4*)(rp + kb * 32 + 4);
        uint4 uu;
        uu.x = bf16pair(x0.x, x0.y);
        uu.y = bf16pair(x0.z, x0.w);
        uu.z = bf16pair(x1.x, x1.y);
        uu.w = bf16pair(x1.z, x1.w);
        wf[g * 4 + s][kb] = __builtin_bit_cast(s16x8, uu);
      }
    }
  }

  bsh[tid] = bhh[tid];
  bsh[256 + tid] = bhh[256 + tid];
  bsh[512 + tid] = bhh[512 + tid];
  hb[tid] = __float2bfloat16(0.0f);
  wa[tid] = watt[tid];
  float h = 0.f;
  __syncthreads();

  for (int t = 0; t < T_DIM; ++t) {
    // prefetch gx for this step; consumed after the MFMA phase (hides latency)
    const float gxr = gx[t * 768 + tid];
    const float gxz = gx[t * 768 + 256 + tid];
    const float gxn = gx[t * 768 + 512 + tid];
    // acc init = b_hh rows (bias folded into gh)
    f32x4 acc[12];
#pragma unroll
    for (int g = 0; g < 3; ++g)
#pragma unroll
      for (int s = 0; s < 4; ++s)
        acc[g * 4 + s] = *(const f32x4*)&bsh[g * 256 + w * 64 + s * 16 + lg * 4];
    // B fragment: h[k = kb*32 + lg*8 + 0..7], same for all 16 cols
#pragma unroll
    for (int kb = 0; kb < 8; ++kb) {
      const s16x8 bf = *(const s16x8*)((const char*)hb + kb * 64 + lg * 16);
#pragma unroll
      for (int tt = 0; tt < 12; ++tt)
        acc[tt] = __builtin_amdgcn_mfma_f32_16x16x32_bf16(wf[tt][kb], bf, acc[tt], 0, 0, 0);
    }
    // publish gh rows: C row = lg*4+q, all cols identical -> lanes lr==0 write
    if (lr == 0) {
#pragma unroll
      for (int g = 0; g < 3; ++g)
#pragma unroll
        for (int s = 0; s < 4; ++s)
          *(f32x4*)&ghs[g * 256 + w * 64 + s * 16 + lg * 4] = acc[g * 4 + s];
    }
    __syncthreads();              // gh visible; also: all hb reads of step t done
    {
      const float r = 1.f / (1.f + __expf(-(gxr + ghs[tid])));
      const float z = 1.f / (1.f + __expf(-(gxz + ghs[256 + tid])));
      const float pn = gxn + r * ghs[512 + tid];
      const float n = 2.f / (1.f + __expf(-2.f * pn)) - 1.f;   // tanh
      h = (1.f - z) * n + z * h;
      hs[t * DH + tid] = h;
      hb[tid] = __float2bfloat16(h);
    }
    __syncthreads();              // h_t visible for step t+1
  }

  // ---- attention epilogue: alpha = softmax(hs @ w_att); out = alpha^T hs ----
#pragma unroll
  for (int tt = 0; tt < 2; ++tt) {
    const int t = tid + tt * 256;
    const float* __restrict__ hr = &hs[(size_t)t * DH];
    float s = 0.f;
#pragma unroll 4
    for (int k = 0; k < DH; k += 4) {
      const float4 hv = *(const float4*)(hr + k);
      const float4 wv4 = *(const float4*)(&wa[k]);
      s = fmaf(hv.x, wv4.x, s); s = fmaf(hv.y, wv4.y, s);
      s = fmaf(hv.z, wv4.z, s); s = fmaf(hv.w, wv4.w, s);
    }
    sc[t] = s;
  }
  __syncthreads();
  if (tid < 64) {
    float m = -1e30f;
#pragma unroll
    for (int i = 0; i < 8; ++i) m = fmaxf(m, sc[tid * 8 + i]);
#pragma unroll
    for (int off = 32; off > 0; off >>= 1) m = fmaxf(m, __shfl_down(m, off));
    if (tid == 0) red[0] = m;
  }
  __syncthreads();
  const float M = red[0];
  sc[tid] = __expf(sc[tid] - M);
  sc[tid + 256] = __expf(sc[tid + 256] - M);
  __syncthreads();
  if (tid < 64) {
    float s = 0.f;
#pragma unroll
    for (int i = 0; i < 8; ++i) s += sc[tid * 8 + i];
#pragma unroll
    for (int off = 32; off > 0; off >>= 1) s += __shfl_down(s, off);
    if (tid == 0) red[1] = s;
  }
  __syncthreads();
  const float inv = 1.f / red[1];
  float a = 0.f;
  for (int t = 0; t < T_DIM; ++t) a = fmaf(sc[t], hs[(size_t)t * DH + tid], a);
  out[tid] = a * inv;
}

extern "C" void kernel_launch(void* const* d_in, const int* in_sizes, int n_in,
                              void* d_out, int out_size, void* d_ws, size_t ws_size,
                              hipStream_t stream) {
  const float* X    = (const float*)d_in[0];
  const float* H    = (const float*)d_in[1];
  const float* Wih  = (const float*)d_in[2];
  const float* Whh  = (const float*)d_in[3];
  const float* bih  = (const float*)d_in[4];
  const float* bhh  = (const float*)d_in[5];
  const float* watt = (const float*)d_in[6];
  float* out = (float*)d_out;

  char* ws = (char*)d_ws;
  float* gx      = (float*)ws;                        // 512*768*4 = 1572864 B
  float* hs      = (float*)(ws + 1572864);            // 512*256*4 = 524288 B
  float* ve      = (float*)(ws + 2097152);            // 524288 B (atomic fallback)
  float* ve_part = (float*)(ws + 2621440);            // 125*512*256*4 = 65536000 B

  const size_t need_part = 2621440 + 65536000;
  const int use_part = (ws_size >= need_part) ? 1 : 0;

  if (!use_part)
    hipMemsetAsync(ve, 0, T_DIM * DIN * sizeof(float), stream);

  k_agg_mfma<<<2 * NCHUNK, 512, 0, stream>>>(X, H, ve, ve_part, use_part);
  k_gx<<<T_DIM, 256, 0, stream>>>(use_part ? ve_part : ve, use_part ? NCHUNK : 1,
                                  Wih, bih, gx);
  k_gru_att<<<1, 256, 0, stream>>>(Whh, bhh, gx, watt, hs, out);
}

// Round 10
// 1027.027 us; speedup vs baseline: 1.1459x; 1.1459x over previous
//
#include <hip/hip_runtime.h>
#include <hip/hip_bf16.h>

#define N_ROWS 100000
#define T_DIM  512
#define DIN    256
#define DH     256
#define KC     800
#define NSTEP  25      // KC / 32
#define NCHUNK 125     // 125 * 800 = 100000 exactly

typedef __attribute__((ext_vector_type(8))) short s16x8;
typedef __attribute__((ext_vector_type(4))) float f32x4;

// pack two f32 into bf16 pair (RTNE), low = lo, high = hi
static __device__ __forceinline__ unsigned bf16pair(float lo, float hi) {
  unsigned a = __builtin_bit_cast(unsigned, lo);
  unsigned b = __builtin_bit_cast(unsigned, hi);
  a = (a + 0x7fffu + ((a >> 16) & 1u)) >> 16;
  b = (b + 0x7fffu + ((b >> 16) & 1u)) & 0xffff0000u;
  return a | b;
}

// ---------------- Kernel 1: ve = H^T @ X as dense bf16 MFMA GEMM, split-K ----
__global__ __launch_bounds__(512, 2) void k_agg_mfma(
    const float* __restrict__ X, const float* __restrict__ Hm,
    float* __restrict__ ve, float* __restrict__ ve_part, int use_part)
{
  __shared__ unsigned smem[8192];   // A: [0,4096) u32, B: [4096,8192) ; 32 KB
  const int tid  = threadIdx.x;
  const int mt   = blockIdx.x & 1;
  const int kc   = blockIdx.x >> 1;
  const int m0   = mt * 256;
  const int k0   = kc * KC;
  const int lane = tid & 63;
  const int wv   = tid >> 6;        // 8 waves: 2 (wm) x 4 (wn)
  const int wm   = wv >> 2, wn = wv & 3;

  f32x4 acc[8][4] = {};

  const int kp0 = tid >> 6;
  const int kp1 = kp0 + 8;
  const int gg  = tid & 63;

  float4 ra0, ra1, ra2, ra3, rb0, rb1, rb2, rb3;

  auto load_tile = [&](int kt) {
    const size_t kb = (size_t)(k0 + kt * 32);
    const float* pa0 = &Hm[(kb + 2 * kp0) * T_DIM + m0 + gg * 4];
    ra0 = *(const float4*)pa0;
    ra1 = *(const float4*)(pa0 + T_DIM);
    const float* pa1 = &Hm[(kb + 2 * kp1) * T_DIM + m0 + gg * 4];
    ra2 = *(const float4*)pa1;
    ra3 = *(const float4*)(pa1 + T_DIM);
    const float* pb0 = &X[(kb + 2 * kp0) * DIN + gg * 4];
    rb0 = *(const float4*)pb0;
    rb1 = *(const float4*)(pb0 + DIN);
    const float* pb1 = &X[(kb + 2 * kp1) * DIN + gg * 4];
    rb2 = *(const float4*)pb1;
    rb3 = *(const float4*)(pb1 + DIN);
  };

  auto store_tile = [&]() {
#pragma unroll
    for (int d = 0; d < 4; ++d) {
      const int m  = gg * 4 + d;
      const int sw = d << 2;
      smem[m * 16 + (kp0 ^ sw)]        = bf16pair(((const float*)&ra0)[d], ((const float*)&ra1)[d]);
      smem[m * 16 + (kp1 ^ sw)]        = bf16pair(((const float*)&ra2)[d], ((const float*)&ra3)[d]);
      smem[4096 + m * 16 + (kp0 ^ sw)] = bf16pair(((const float*)&rb0)[d], ((const float*)&rb1)[d]);
      smem[4096 + m * 16 + (kp1 ^ sw)] = bf16pair(((const float*)&rb2)[d], ((const float*)&rb3)[d]);
    }
  };

  auto compute = [&]() {
    const uint4* sv = (const uint4*)smem;
    s16x8 af[8], bfr[4];
#pragma unroll
    for (int fm = 0; fm < 8; ++fm) {
      const int m = wm * 128 + fm * 16 + (lane & 15);
      af[fm] = __builtin_bit_cast(s16x8, sv[m * 4 + ((lane >> 4) ^ (m & 3))]);
    }
#pragma unroll
    for (int fn = 0; fn < 4; ++fn) {
      const int n = wn * 64 + fn * 16 + (lane & 15);
      bfr[fn] = __builtin_bit_cast(s16x8, sv[1024 + n * 4 + ((lane >> 4) ^ (n & 3))]);
    }
#pragma unroll
    for (int fm = 0; fm < 8; ++fm)
#pragma unroll
      for (int fn = 0; fn < 4; ++fn)
        acc[fm][fn] = __builtin_amdgcn_mfma_f32_16x16x32_bf16(af[fm], bfr[fn], acc[fm][fn], 0, 0, 0);
  };

  load_tile(0);
  store_tile();
  for (int kt = 0; kt < NSTEP; ++kt) {
    __syncthreads();
    if (kt + 1 < NSTEP) load_tile(kt + 1);
    compute();
    __syncthreads();
    if (kt + 1 < NSTEP) store_tile();
  }

  if (use_part) {
    float* dst = ve_part + (size_t)kc * (512 * 256);
#pragma unroll
    for (int fm = 0; fm < 8; ++fm) {
      const int r0 = m0 + wm * 128 + fm * 16 + (lane >> 4) * 4;
#pragma unroll
      for (int fn = 0; fn < 4; ++fn) {
        const int cc = wn * 64 + fn * 16 + (lane & 15);
#pragma unroll
        for (int q = 0; q < 4; ++q)
          dst[(size_t)(r0 + q) * 256 + cc] = acc[fm][fn][q];
      }
    }
  } else {
#pragma unroll
    for (int fm = 0; fm < 8; ++fm) {
      const int r0 = m0 + wm * 128 + fm * 16 + (lane >> 4) * 4;
#pragma unroll
      for (int fn = 0; fn < 4; ++fn) {
        const int cc = wn * 64 + fn * 16 + (lane & 15);
#pragma unroll
        for (int q = 0; q < 4; ++q)
          atomicAdd(&ve[(size_t)(r0 + q) * 256 + cc], acc[fm][fn][q]);
      }
    }
  }
}

// ---------------- Kernel 2: reduce split-K partials + gx = ve @ W_ih^T + b ----
__global__ __launch_bounds__(256) void k_gx(
    const float* __restrict__ vesrc, int npart,
    const float* __restrict__ Wih, const float* __restrict__ bih,
    float* __restrict__ gx)
{
  __shared__ float vl[DIN];
  const int t = blockIdx.x, j = threadIdx.x;
  float s = 0.f;
  for (int p = 0; p < npart; ++p) s += vesrc[(size_t)p * (512 * 256) + t * DIN + j];
  vl[j] = s;
  __syncthreads();
  float a0 = bih[j], a1 = bih[256 + j], a2 = bih[512 + j];
  const float* __restrict__ w0 = &Wih[(size_t)j * DIN];
  const float* __restrict__ w1 = &Wih[(size_t)(j + 256) * DIN];
  const float* __restrict__ w2 = &Wih[(size_t)(j + 512) * DIN];
#pragma unroll 4
  for (int k = 0; k < DIN; ++k) {
    const float v = vl[k];
    a0 = fmaf(w0[k], v, a0);
    a1 = fmaf(w1[k], v, a1);
    a2 = fmaf(w2[k], v, a2);
  }
  gx[t * 768 + j]       = a0;
  gx[t * 768 + 256 + j] = a1;
  gx[t * 768 + 512 + j] = a2;
}

// ---------------- Kernel 2b: pack W_hh into bf16 MFMA fragments --------------
// Fragment layout: frag index c = ((w*48 + s*8 + kb)*64 + l); lane l holds
// A[m = l&15][k = kb*32 + (l>>4)*8 .. +8] of rows [w*96 + s*16, +16).
__global__ __launch_bounds__(256) void k_pack(
    const float* __restrict__ Whh, uint4* __restrict__ wpack)
{
  const int c = blockIdx.x * 256 + threadIdx.x;   // 0..24575
  const int l = c & 63;
  const int f = (c >> 6) % 48;
  const int w = c / (48 * 64);
  const int s = f >> 3, kb = f & 7;
  const int row = w * 96 + s * 16 + (l & 15);
  const int col = kb * 32 + (l >> 4) * 8;
  const float* p = &Whh[(size_t)row * DH + col];
  uint4 u;
  u.x = bf16pair(p[0], p[1]);
  u.y = bf16pair(p[2], p[3]);
  u.z = bf16pair(p[4], p[5]);
  u.w = bf16pair(p[6], p[7]);
  wpack[c] = u;
}

// ---------------- Kernel 3: GRU scan, W split across regs + LDS + L2 stream --
// R2-R9 lesson: RA budgets ~2 blocks/CU (~256KB regs/CU) no matter what ->
// 393KB W can never be all-register. Split instead: per wave (8 waves, 512thr)
// 48 frags = 6 row-tiles x 8 k-blocks:
//   kb 0-1  -> registers   (12 frags = 48 VGPR/thread, 96KB/CU)
//   kb 2-4  -> LDS         (18 frags/wave = 147KB/CU, LDS previously unused!)
//   kb 5-7  -> L2 stream   (18 frags/wave = 144KB/step @ ~64B/cy ~= 0.95us)
// Reg tally ~116 <= proven 128 grant. Streamed region is L2-resident (read
// every step). Single-buffer batch rotation: issue kb5 at top (latency hides
// under reg+LDS MFMA phase), reissue after each consume; 2 waves/SIMD TLP
// covers residual latency since BW is the binding constraint.
__global__ __launch_bounds__(512) void k_gru_att(
    const uint4* __restrict__ wpack, const float* __restrict__ bhh,
    const float* __restrict__ gx, const float* __restrict__ watt,
    float* __restrict__ hs, float* __restrict__ out)
{
  __shared__ uint4 wlds[18 * 8 * 64];   // 147456 B of W fragments
  __shared__ __hip_bfloat16 hb[DH];     // h_{t-1} bf16, 512 B
  __shared__ float ghs[768];            // gh rows / attn partials (reuse)
  __shared__ float bsh[768];            // b_hh (acc init) / watt (epilogue reuse)
  __shared__ float sc[T_DIM];           // attention scores
  __shared__ float red[2];

  const int tid = threadIdx.x;
  const int w   = tid >> 6;   // wave 0..7
  const int l   = tid & 63;
  const int lg  = l >> 4;     // k-group / row-quad selector
  const int lr  = l & 15;

  const uint4* __restrict__ wsv = wpack + (size_t)w * 48 * 64;  // this wave's frags

  // registers: kb 0..1 for all 6 row-tiles (48 VGPRs)
  s16x8 wf[12];
#pragma unroll
  for (int s = 0; s < 6; ++s)
#pragma unroll
    for (int kb = 0; kb < 2; ++kb)
      wf[s * 2 + kb] = __builtin_bit_cast(s16x8, wsv[((s << 3) + kb) * 64 + l]);

  // LDS: kb 2..4 for all 6 row-tiles (18 frags/wave)
#pragma unroll
  for (int j = 0; j < 18; ++j) {
    const int s = j / 3, kb = 2 + j % 3;
    wlds[(w * 18 + j) * 64 + l] = wsv[((s << 3) + kb) * 64 + l];
  }

  bsh[tid] = bhh[tid];
  if (tid < 256) {
    bsh[512 + tid] = bhh[512 + tid];
    hb[tid] = __float2bfloat16(0.0f);
  }
  float h = 0.f;
  __syncthreads();

  for (int t = 0; t < T_DIM; ++t) {
    // stream batch kb=5 issued first: latency hides under reg+LDS MFMA phase
    uint4 st[6];
#pragma unroll
    for (int s = 0; s < 6; ++s) st[s] = wsv[((s << 3) + 5) * 64 + l];

    float gxr = 0.f, gxz = 0.f, gxn = 0.f;
    if (tid < 256) {
      gxr = gx[t * 768 + tid];
      gxz = gx[t * 768 + 256 + tid];
      gxn = gx[t * 768 + 512 + tid];
    }

    f32x4 acc[6];
#pragma unroll
    for (int s = 0; s < 6; ++s)
      acc[s] = *(const f32x4*)&bsh[w * 96 + s * 16 + lg * 4];

    // kb 0..1 from registers
#pragma unroll
    for (int kb = 0; kb < 2; ++kb) {
      const s16x8 bf = *(const s16x8*)((const char*)hb + kb * 64 + lg * 16);
#pragma unroll
      for (int s = 0; s < 6; ++s)
        acc[s] = __builtin_amdgcn_mfma_f32_16x16x32_bf16(wf[s * 2 + kb], bf, acc[s], 0, 0, 0);
    }
    // kb 2..4 from LDS
#pragma unroll
    for (int kb = 2; kb < 5; ++kb) {
      const s16x8 bf = *(const s16x8*)((const char*)hb + kb * 64 + lg * 16);
#pragma unroll
      for (int s = 0; s < 6; ++s) {
        const s16x8 a = __builtin_bit_cast(s16x8, wlds[(w * 18 + s * 3 + (kb - 2)) * 64 + l]);
        acc[s] = __builtin_amdgcn_mfma_f32_16x16x32_bf16(a, bf, acc[s], 0, 0, 0);
      }
    }
    // kb 5..7 streamed from L2, single-buffer rotation
#pragma unroll
    for (int b = 0; b < 3; ++b) {
      const int kb = 5 + b;
      const s16x8 bf = *(const s16x8*)((const char*)hb + kb * 64 + lg * 16);
#pragma unroll
      for (int s = 0; s < 6; ++s)
        acc[s] = __builtin_amdgcn_mfma_f32_16x16x32_bf16(__builtin_bit_cast(s16x8, st[s]), bf, acc[s], 0, 0, 0);
      if (b < 2) {
#pragma unroll
        for (int s = 0; s < 6; ++s) st[s] = wsv[((s << 3) + 6 + b) * 64 + l];
      }
    }

    // publish gh rows: C row = lg*4+q, all 16 cols identical -> lr==0 writes
    if (lr == 0) {
#pragma unroll
      for (int s = 0; s < 6; ++s)
        *(f32x4*)&ghs[w * 96 + s * 16 + lg * 4] = acc[s];
    }
    __syncthreads();              // gh visible; all hb reads of step t done
    if (tid < 256) {
      const float r = 1.f / (1.f + __expf(-(gxr + ghs[tid])));
      const float z = 1.f / (1.f + __expf(-(gxz + ghs[256 + tid])));
      const float pn = gxn + r * ghs[512 + tid];
      const float n = 2.f / (1.f + __expf(-2.f * pn)) - 1.f;   // tanh
      h = (1.f - z) * n + z * h;
      hs[t * DH + tid] = h;
      hb[tid] = __float2bfloat16(h);
    }
    __syncthreads();              // h_t visible for step t+1
  }

  // ---- attention epilogue: alpha = softmax(hs @ w_att); out = alpha^T hs ----
  if (tid < 256) bsh[tid] = watt[tid];   // bsh reused as watt stage
  __syncthreads();
  {
    const float* __restrict__ hr = &hs[(size_t)tid * DH];   // one t per thread
    float s = 0.f;
#pragma unroll 4
    for (int k = 0; k < DH; k += 4) {
      const float4 hv = *(const float4*)(hr + k);
      const float4 wv4 = *(const float4*)(&bsh[k]);
      s = fmaf(hv.x, wv4.x, s); s = fmaf(hv.y, wv4.y, s);
      s = fmaf(hv.z, wv4.z, s); s = fmaf(hv.w, wv4.w, s);
    }
    sc[tid] = s;
  }
  __syncthreads();
  if (tid < 64) {
    float m = -1e30f;
#pragma unroll
    for (int i = 0; i < 8; ++i) m = fmaxf(m, sc[tid * 8 + i]);
#pragma unroll
    for (int off = 32; off > 0; off >>= 1) m = fmaxf(m, __shfl_down(m, off));
    if (tid == 0) red[0] = m;
  }
  __syncthreads();
  const float M = red[0];
  sc[tid] = __expf(sc[tid] - M);
  __syncthreads();
  if (tid < 64) {
    float s = 0.f;
#pragma unroll
    for (int i = 0; i < 8; ++i) s += sc[tid * 8 + i];
#pragma unroll
    for (int off = 32; off > 0; off >>= 1) s += __shfl_down(s, off);
    if (tid == 0) red[1] = s;
  }
  __syncthreads();
  const float inv = 1.f / red[1];
  // weighted sum: two half-ranges of t in parallel, partials in ghs (reused)
  {
    const int j = tid & 255, half = tid >> 8;
    float acc = 0.f;
    for (int t = half * 256; t < half * 256 + 256; ++t)
      acc = fmaf(sc[t], hs[(size_t)t * DH + j], acc);
    ghs[half * 256 + j] = acc;
  }
  __syncthreads();
  if (tid < 256) out[tid] = (ghs[tid] + ghs[256 + tid]) * inv;
}

extern "C" void kernel_launch(void* const* d_in, const int* in_sizes, int n_in,
                              void* d_out, int out_size, void* d_ws, size_t ws_size,
                              hipStream_t stream) {
  const float* X    = (const float*)d_in[0];
  const float* H    = (const float*)d_in[1];
  const float* Wih  = (const float*)d_in[2];
  const float* Whh  = (const float*)d_in[3];
  const float* bih  = (const float*)d_in[4];
  const float* bhh  = (const float*)d_in[5];
  const float* watt = (const float*)d_in[6];
  float* out = (float*)d_out;

  char* ws = (char*)d_ws;
  float* gx      = (float*)ws;                        // 1572864 B
  float* hs      = (float*)(ws + 1572864);            // 524288 B
  float* ve      = (float*)(ws + 2097152);            // 524288 B (atomic fallback)
  uint4* wpack   = (uint4*)(ws + 2621440);            // 393216 B
  float* ve_part = (float*)(ws + 3014656);            // 65536000 B

  const size_t need_part = 3014656ull + 65536000ull;
  const int use_part = (ws_size >= need_part) ? 1 : 0;

  if (!use_part)
    hipMemsetAsync(ve, 0, T_DIM * DIN * sizeof(float), stream);

  k_pack<<<96, 256, 0, stream>>>(Whh, wpack);
  k_agg_mfma<<<2 * NCHUNK, 512, 0, stream>>>(X, H, ve, ve_part, use_part);
  k_gx<<<T_DIM, 256, 0, stream>>>(use_part ? ve_part : ve, use_part ? NCHUNK : 1,
                                  Wih, bih, gx);
  k_gru_att<<<1, 512, 0, stream>>>(wpack, bhh, gx, watt, hs, out);
}